// Round 5
// baseline (565.876 us; speedup 1.0000x reference)
//
#include <hip/hip_runtime.h>

#define HH 96
#define WW 128
#define PP 9
#define RAD 4
#define YT 2                    // y rows per block
#define CCH 8                   // channels per chunk
#define NCHUNK 16
#define TDI 3                   // di values per block (grid.z splits di 3-way)
#define ROWS2 (YT + TDI - 1)    // 4 in2 rows staged
#define GS 137                  // granule stride per row (136 + 1 pad)
#define NG2 (ROWS2 * 136)       // 544 in2 granules per chunk
#define NG1 (YT * WW)           // 256 in1 granules per chunk
#define NT 384                  // 2 * 3 * 64 threads = 6 full waves
#define PX 2                    // x pixels per thread
#define CHS (HH * WW)           // channel plane stride

// clang's amdgcn builtins use __fp16 vectors ('h' encoding), not _Float16.
typedef __fp16 h2v __attribute__((ext_vector_type(2)));
union HU { unsigned int u; h2v h; };

__device__ __forceinline__ unsigned int pk(float a, float b) {
    HU r; r.h = __builtin_amdgcn_cvt_pkrtz(a, b); return r.u;
}
__device__ __forceinline__ float dot2(unsigned int a, unsigned int b, float c) {
    HU ua, ub; ua.u = a; ub.u = b;
    return __builtin_amdgcn_fdot2(ua.h, ub.h, c, false);
}
// granule-level XOR swizzle: spreads strided granule reads across bank groups
__device__ __forceinline__ int swz(int g) { return g ^ ((g >> 3) & 7); }

__global__ __launch_bounds__(NT, 6)
void corr_kernel(const float* __restrict__ in1, const float* __restrict__ in2,
                 float* __restrict__ out)
{
    __shared__ uint4 s2[2][ROWS2 * GS];   // in2 window rows (dbuf)
    __shared__ uint4 s1[2][YT * GS];      // in1 rows (dbuf)

    const int tid = threadIdx.x;
    const int y0  = blockIdx.x * YT;
    const int b   = blockIdx.y;
    const int dib = blockIdx.z * TDI;

    // compute role: (yl, di3, xg); one wave = one (yl,di3) x 64 xg
    const int yl  = tid / (TDI * 64);
    const int rem = tid - yl * (TDI * 64);
    const int di3 = rem >> 6;
    const int xg  = rem & 63;
    const int x0  = xg * PX;

    const float* b1 = in1 + (size_t)b * 128 * CHS;
    const float* b2 = in2 + (size_t)b * 128 * CHS;

    // ---- staging descriptors (3 granules/thread, k=0,1 full, k=2: tid<32) ----
    // k=0: in2 granule s = tid (< 544)
    const int r0  = tid / 136;
    const int l0  = tid - r0 * 136;
    const int gy0 = y0 - RAD + dib + r0;
    const int gx0 = l0 - RAD;
    const bool v0 = ((unsigned)gy0 < HH) && ((unsigned)gx0 < WW);
    const float* p0 = b2 + (gy0 * WW + gx0);
    const int d0  = r0 * GS + swz(l0);                 // -> s2

    // k=1: s = tid + 384: in2 if s<544 (tid<160) else in1 t = s-544 in [0,224)
    const int s1i   = tid + NT;
    const bool k1in2 = (s1i < NG2);
    const int r1a = s1i / 136;
    const int l1a = s1i - r1a * 136;
    const int gy1 = y0 - RAD + dib + r1a;
    const int gx1 = l1a - RAD;
    const int t1  = s1i - NG2;
    const int r1b = t1 >> 7;
    const int x1b = t1 & 127;
    const bool v1 = k1in2 ? (((unsigned)gy1 < HH) && ((unsigned)gx1 < WW)) : true;
    const float* p1 = k1in2 ? (b2 + (gy1 * WW + gx1))
                            : (b1 + ((y0 + r1b) * WW + x1b));
    const int d1  = k1in2 ? (r1a * GS + swz(l1a)) : (r1b * GS + swz(x1b));

    // k=2: tid<32: in1 t = tid+224 -> row 1, x = 96+tid
    const bool act2 = (tid < 32);
    const float* p2 = b1 + ((y0 + 1) * WW + (96 + tid));
    const int d2  = GS + swz(96 + tid);                // -> s1 row 1

    float fl[3][8];
    float acc[PP][PX];
    #pragma unroll
    for (int j = 0; j < PP; ++j) { acc[j][0] = 0.f; acc[j][1] = 0.f; }

#define LOADCHUNK(cc) do { const int co_ = (cc) * CCH * CHS;                      \
    _Pragma("unroll") for (int j = 0; j < 8; ++j)                                 \
        fl[0][j] = v0 ? p0[co_ + j * CHS] : 0.f;                                  \
    _Pragma("unroll") for (int j = 0; j < 8; ++j)                                 \
        fl[1][j] = v1 ? p1[co_ + j * CHS] : 0.f;                                  \
    if (act2) { _Pragma("unroll") for (int j = 0; j < 8; ++j)                     \
        fl[2][j] = p2[co_ + j * CHS]; } } while (0)

#define WRITECHUNK(buf) do {                                                      \
    uint4 g0_; g0_.x = pk(fl[0][0], fl[0][1]); g0_.y = pk(fl[0][2], fl[0][3]);    \
    g0_.z = pk(fl[0][4], fl[0][5]); g0_.w = pk(fl[0][6], fl[0][7]);               \
    s2[buf][d0] = g0_;                                                            \
    uint4 g1_; g1_.x = pk(fl[1][0], fl[1][1]); g1_.y = pk(fl[1][2], fl[1][3]);    \
    g1_.z = pk(fl[1][4], fl[1][5]); g1_.w = pk(fl[1][6], fl[1][7]);               \
    if (k1in2) s2[buf][d1] = g1_; else s1[buf][d1] = g1_;                         \
    if (act2) { uint4 g2_; g2_.x = pk(fl[2][0], fl[2][1]);                        \
        g2_.y = pk(fl[2][2], fl[2][3]); g2_.z = pk(fl[2][4], fl[2][5]);           \
        g2_.w = pk(fl[2][6], fl[2][7]); s1[buf][d2] = g2_; } } while (0)

#define COMPUTE(buf) do {                                                         \
    const uint4* ar_ = &s1[buf][yl * GS];                                         \
    const uint4 a0_ = ar_[swz(x0)];                                               \
    const uint4 a1_ = ar_[swz(x0 + 1)];                                           \
    const uint4* r2_ = &s2[buf][(yl + di3) * GS];                                 \
    _Pragma("unroll") for (int w = 0; w < PX + PP - 1; ++w) {                     \
        const uint4 v_ = r2_[swz(x0 + w)];                                        \
        if (w <= PP - 1) { float t = acc[w][0];                                   \
            t = dot2(v_.x, a0_.x, t); t = dot2(v_.y, a0_.y, t);                   \
            t = dot2(v_.z, a0_.z, t); t = dot2(v_.w, a0_.w, t); acc[w][0] = t; }  \
        if (w >= 1) { float t = acc[w - 1][1];                                    \
            t = dot2(v_.x, a1_.x, t); t = dot2(v_.y, a1_.y, t);                   \
            t = dot2(v_.z, a1_.z, t); t = dot2(v_.w, a1_.w, t); acc[w - 1][1] = t; } \
    } } while (0)

    // prologue: stage chunk 0 into buf 0
    LOADCHUNK(0);
    WRITECHUNK(0);
    __syncthreads();

    #pragma unroll 2
    for (int cc = 0; cc < NCHUNK; ++cc) {
        const int cur = cc & 1;
        if (cc + 1 < NCHUNK) LOADCHUNK(cc + 1);   // global loads in flight
        COMPUTE(cur);                             // dot2 on current buffer
        if (cc + 1 < NCHUNK) WRITECHUNK(cur ^ 1); // land next tile
        __syncthreads();
    }

    // epilogue: disjoint stores (this block owns di = dib..dib+2)
    const int y  = y0 + yl;
    const int di = dib + di3;
    #pragma unroll
    for (int dj = 0; dj < PP; ++dj) {
        float* op = out + ((((size_t)(b * PP + di)) * PP + dj) * HH + y) * WW + x0;
        *reinterpret_cast<float2*>(op) = make_float2(acc[dj][0], acc[dj][1]);
    }
}

extern "C" void kernel_launch(void* const* d_in, const int* in_sizes, int n_in,
                              void* d_out, int out_size, void* d_ws, size_t ws_size,
                              hipStream_t stream) {
    const float* in1 = (const float*)d_in[0];
    const float* in2 = (const float*)d_in[1];
    float* out = (float*)d_out;
    dim3 grid(HH / YT, 8, 3);   // 48 x 8 x 3 = 1152 blocks (~4.5/CU)
    dim3 block(NT);
    corr_kernel<<<grid, block, 0, stream>>>(in1, in2, out);
}

// Round 6
// 164.839 us; speedup vs baseline: 3.4329x; 3.4329x over previous
//
#include <hip/hip_runtime.h>

#define HH 96
#define WW 128
#define PP 9
#define RAD 4
#define YT 2                    // y rows per block
#define CCH 8                   // channels per chunk
#define NCHUNK 16
#define TDI 3                   // di values per block (grid.z splits di 3-way)
#define ROWS2 (YT + TDI - 1)    // 4 in2 rows staged
#define GS 137                  // granule stride per row (136 + 1 pad)
#define NG2 (ROWS2 * 136)       // 544 in2 granules per chunk
#define NT 384                  // 2 * 3 * 64 threads = 6 full waves
#define PX 2                    // x pixels per thread
#define CHS (HH * WW)           // channel plane stride

// clang's amdgcn builtins use __fp16 vectors ('h' encoding), not _Float16.
typedef __fp16 h2v __attribute__((ext_vector_type(2)));
union HU { unsigned int u; h2v h; };

__device__ __forceinline__ unsigned int pk(float a, float b) {
    HU r; r.h = __builtin_amdgcn_cvt_pkrtz(a, b); return r.u;
}
__device__ __forceinline__ float dot2(unsigned int a, unsigned int b, float c) {
    HU ua, ub; ua.u = a; ub.u = b;
    return __builtin_amdgcn_fdot2(ua.h, ub.h, c, false);
}
// granule-level XOR swizzle: spreads strided granule reads across bank groups
__device__ __forceinline__ int swz(int g) { return g ^ ((g >> 3) & 7); }

__global__ __launch_bounds__(NT, 6)
void corr_kernel(const float* __restrict__ in1, const float* __restrict__ in2,
                 float* __restrict__ out)
{
    // double-buffered LDS; one barrier per chunk (stage k+1 hits the other buf)
    __shared__ uint4 s2[2][ROWS2 * GS];   // in2 window rows
    __shared__ uint4 s1[2][YT * GS];      // in1 rows

    const int tid = threadIdx.x;
    const int y0  = blockIdx.x * YT;
    const int b   = blockIdx.y;
    const int dib = blockIdx.z * TDI;

    // compute role: (yl, di3, xg); one wave = one (yl,di3) x 64 xg
    const int yl  = tid / (TDI * 64);
    const int rem = tid - yl * (TDI * 64);
    const int di3 = rem >> 6;
    const int xg  = rem & 63;
    const int x0  = xg * PX;

    const float* b1 = in1 + (size_t)b * 128 * CHS;
    const float* b2 = in2 + (size_t)b * 128 * CHS;

    // ---- staging descriptors (verified round 5) ----
    // k=0: in2 granule s = tid (< 544)
    const int r0  = tid / 136;
    const int l0  = tid - r0 * 136;
    const int gy0 = y0 - RAD + dib + r0;
    const int gx0 = l0 - RAD;
    const bool v0 = ((unsigned)gy0 < HH) && ((unsigned)gx0 < WW);
    const float* p0 = b2 + (gy0 * WW + gx0);
    const int d0  = r0 * GS + swz(l0);                 // -> s2

    // k=1: s = tid + 384: in2 if s<544 (tid<160) else in1 t = s-544 in [0,224)
    const int s1i   = tid + NT;
    const bool k1in2 = (s1i < NG2);
    const int r1a = s1i / 136;
    const int l1a = s1i - r1a * 136;
    const int gy1 = y0 - RAD + dib + r1a;
    const int gx1 = l1a - RAD;
    const int t1  = s1i - NG2;
    const int r1b = t1 >> 7;
    const int x1b = t1 & 127;
    const bool v1 = k1in2 ? (((unsigned)gy1 < HH) && ((unsigned)gx1 < WW)) : true;
    const float* p1 = k1in2 ? (b2 + (gy1 * WW + gx1))
                            : (b1 + ((y0 + r1b) * WW + x1b));
    const int d1  = k1in2 ? (r1a * GS + swz(l1a)) : (r1b * GS + swz(x1b));

    // k=2: tid<32: in1 row 1, x = 96+tid
    const bool act2 = (tid < 32);
    const float* p2 = b1 + ((y0 + 1) * WW + (96 + tid));
    const int d2  = GS + swz(96 + tid);                // -> s1 row 1

    float acc[PP][PX];
    #pragma unroll
    for (int j = 0; j < PP; ++j) { acc[j][0] = 0.f; acc[j][1] = 0.f; }

    for (int cc = 0; cc < NCHUNK; ++cc) {
        const int buf = cc & 1;
        const int co  = cc * CCH * CHS;

        // ---- stage directly (transient locals only: no cross-phase liveness)
        {
            float f[8];
            #pragma unroll
            for (int j = 0; j < 8; ++j) f[j] = v0 ? p0[co + j * CHS] : 0.f;
            uint4 g;
            g.x = pk(f[0], f[1]); g.y = pk(f[2], f[3]);
            g.z = pk(f[4], f[5]); g.w = pk(f[6], f[7]);
            s2[buf][d0] = g;
        }
        {
            float f[8];
            #pragma unroll
            for (int j = 0; j < 8; ++j) f[j] = v1 ? p1[co + j * CHS] : 0.f;
            uint4 g;
            g.x = pk(f[0], f[1]); g.y = pk(f[2], f[3]);
            g.z = pk(f[4], f[5]); g.w = pk(f[6], f[7]);
            if (k1in2) s2[buf][d1] = g; else s1[buf][d1] = g;
        }
        if (act2) {
            float f[8];
            #pragma unroll
            for (int j = 0; j < 8; ++j) f[j] = p2[co + j * CHS];
            uint4 g;
            g.x = pk(f[0], f[1]); g.y = pk(f[2], f[3]);
            g.z = pk(f[4], f[5]); g.w = pk(f[6], f[7]);
            s1[buf][d2] = g;
        }
        __syncthreads();

        // ---- compute from LDS ----
        {
            const uint4* ar = &s1[buf][yl * GS];
            const uint4 a0 = ar[swz(x0)];
            const uint4 a1 = ar[swz(x0 + 1)];
            const uint4* r2 = &s2[buf][(yl + di3) * GS];
            #pragma unroll
            for (int w = 0; w < PX + PP - 1; ++w) {
                const uint4 v = r2[swz(x0 + w)];
                if (w <= PP - 1) {
                    float t = acc[w][0];
                    t = dot2(v.x, a0.x, t); t = dot2(v.y, a0.y, t);
                    t = dot2(v.z, a0.z, t); t = dot2(v.w, a0.w, t);
                    acc[w][0] = t;
                }
                if (w >= 1) {
                    float t = acc[w - 1][1];
                    t = dot2(v.x, a1.x, t); t = dot2(v.y, a1.y, t);
                    t = dot2(v.z, a1.z, t); t = dot2(v.w, a1.w, t);
                    acc[w - 1][1] = t;
                }
            }
        }
        // no trailing barrier: next stage writes buf^1; the sync in the next
        // iteration orders compute(cc) before stage(cc+2) overwrites buf.
    }

    // epilogue: disjoint stores (this block owns di = dib..dib+2)
    const int y  = y0 + yl;
    const int di = dib + di3;
    #pragma unroll
    for (int dj = 0; dj < PP; ++dj) {
        float* op = out + ((((size_t)(b * PP + di)) * PP + dj) * HH + y) * WW + x0;
        *reinterpret_cast<float2*>(op) = make_float2(acc[dj][0], acc[dj][1]);
    }
}

extern "C" void kernel_launch(void* const* d_in, const int* in_sizes, int n_in,
                              void* d_out, int out_size, void* d_ws, size_t ws_size,
                              hipStream_t stream) {
    const float* in1 = (const float*)d_in[0];
    const float* in2 = (const float*)d_in[1];
    float* out = (float*)d_out;
    dim3 grid(HH / YT, 8, 3);   // 48 x 8 x 3 = 1152 blocks (~4.5/CU)
    dim3 block(NT);
    corr_kernel<<<grid, block, 0, stream>>>(in1, in2, out);
}